// Round 1
// baseline (1221.609 us; speedup 1.0000x reference)
//
#include <hip/hip_runtime.h>
#include <hip/hip_cooperative_groups.h>

typedef float f32x4 __attribute__((ext_vector_type(4)));
typedef short s16x8 __attribute__((ext_vector_type(8)));
typedef unsigned int u32;

namespace cg = cooperative_groups;

// ---------------- problem constants ----------------
#define B_    32
#define T_    64
#define TCAP_ 63
#define V_    32000
#define IMGD_ 20480
#define E_    512
#define H_    500
#define KP_   512      // padded K (hidden) for MFMA

// ---------------- ws layout (bytes) ----------------
#define OFF_X      0ul          // x [2048][512] f32
#define OFF_XZ     4194304ul    // xz [64][32][2000] f32 (t-major)
#define OFF_HPAD   20578304ul   // hpad [2][32][512] bf16 (double-buffered h state)
#define OFF_HS     20643840ul   // hs [2048][512] bf16 (all h outputs, K-padded)
#define OFF_UPREP  22740992ul   // uprep [32 wg][64 c][512 k] bf16 (U slices, n-major)
#define OFF_WT     24838144ul   // wt [32000][512] bf16 (W_out^T, K-padded)
#define OFF_RS     57606144ul   // rowsum [2048] f32

__device__ __forceinline__ short bf16rn(float f) {
  u32 u = __float_as_uint(f);
  u += 0x7fff + ((u >> 16) & 1);
  return (short)(u >> 16);
}
__device__ __forceinline__ float sigf(float x) {
  return 1.0f / (1.0f + __expf(-x));
}
__device__ __forceinline__ void gload_lds16(const void* g, void* l) {
  __builtin_amdgcn_global_load_lds((const __attribute__((address_space(1))) void*)g,
                                   (__attribute__((address_space(3))) void*)l, 16, 0, 0);
}

// ---------------- init: x rows (bias / gather), hpad=0, rowsum=0 ----------------
__global__ __launch_bounds__(256) void k_init(const float* __restrict__ bimg,
                                              const float* __restrict__ emb,
                                              const int* __restrict__ cap,
                                              float* __restrict__ x,
                                              u32* __restrict__ hpad_u32,
                                              float* __restrict__ rowsum) {
  int i = blockIdx.x * 256 + threadIdx.x;
  if (i < 262144) {                 // x: 2048 rows * 128 f4
    int m = i >> 7, j4 = i & 127;
    int b = m >> 6, t = m & 63;
    f32x4 v;
    if (t == 0) v = *(const f32x4*)(bimg + j4 * 4);
    else {
      int r = cap[b * TCAP_ + (t - 1)];
      v = *(const f32x4*)(emb + (size_t)r * E_ + j4 * 4);
    }
    *(f32x4*)(x + (size_t)m * E_ + j4 * 4) = v;
  } else if (i < 262144 + 16384) {  // hpad (both buffers): 65536 B = 16384 u32
    hpad_u32[i - 262144] = 0u;
  } else if (i < 262144 + 16384 + 512) {
    int k = i - 262144 - 16384;
    *(f32x4*)(rowsum + k * 4) = (f32x4){0.f, 0.f, 0.f, 0.f};
  }
}

// ---------------- image-embed GEMM: atomicAdd into x rows t=0 ----------------
// grid 128 = 8 col-tiles(64) x 16 k-splits(1280), 256 thr
__global__ __launch_bounds__(256) void k_img(const float* __restrict__ img,
                                             const float* __restrict__ W,
                                             float* __restrict__ x) {
  __shared__ float simg[32][128];
  int ct = blockIdx.x & 7;
  int ks = blockIdx.x >> 3;
  int tid = threadIdx.x;
  int j = tid & 63, bq = tid >> 6;
  int col = ct * 64 + j;
  float acc[8] = {0.f, 0.f, 0.f, 0.f, 0.f, 0.f, 0.f, 0.f};
  int kbeg = ks * 1280;
  for (int k0 = kbeg; k0 < kbeg + 1280; k0 += 128) {
    __syncthreads();
    for (int u = tid; u < 32 * 32; u += 256) {
      int b = u >> 5, kq = (u & 31) * 4;
      *(f32x4*)&simg[b][kq] = *(const f32x4*)(img + (size_t)b * IMGD_ + k0 + kq);
    }
    __syncthreads();
    for (int k = 0; k < 128; ++k) {
      float w = W[(size_t)(k0 + k) * E_ + col];
#pragma unroll
      for (int r = 0; r < 8; ++r) acc[r] += simg[bq * 8 + r][k] * w;
    }
  }
#pragma unroll
  for (int r = 0; r < 8; ++r) {
    int b = bq * 8 + r;
    atomicAdd(x + (size_t)b * T_ * E_ + col, acc[r]);
  }
}

// ---------------- xz = x @ W_lstm + b_lstm (f32 tiled), store [t][b][2000] -------
// grid 1024 = 32 m-tiles x 32 n-tiles, 256 thr, thread tile 4x4, BK=32
__global__ __launch_bounds__(256) void k_xz(const float* __restrict__ A,
                                            const float* __restrict__ Wl,
                                            const float* __restrict__ bl,
                                            float* __restrict__ xz) {
  __shared__ float sA[32][68];  // [k][m]
  __shared__ float sB[32][68];  // [k][n]
  int mt = blockIdx.x & 31, nt = blockIdx.x >> 5;
  int m0 = mt * 64, n0 = nt * 64;
  int tid = threadIdx.x;
  int tx = tid & 15, ty = tid >> 4;
  float acc[4][4] = {};
  for (int kb = 0; kb < 512; kb += 32) {
    __syncthreads();
    for (int u = tid; u < 512; u += 256) {           // A: 64 rows x 8 f4
      int r = u >> 3, kq = (u & 7) * 4;
      f32x4 v = *(const f32x4*)(A + (size_t)(m0 + r) * E_ + kb + kq);
      sA[kq + 0][r] = v.x; sA[kq + 1][r] = v.y; sA[kq + 2][r] = v.z; sA[kq + 3][r] = v.w;
    }
    for (int u = tid; u < 512; u += 256) {           // B: 32 k x 16 f4
      int kk = u >> 4, nj = (u & 15) * 4;
      int n = n0 + nj;
      f32x4 v = (f32x4){0.f, 0.f, 0.f, 0.f};
      if (n < 2000) v = *(const f32x4*)(Wl + (size_t)(kb + kk) * 2000 + n);
      *(f32x4*)&sB[kk][nj] = v;
    }
    __syncthreads();
    for (int k = 0; k < 32; ++k) {
      f32x4 a4 = *(const f32x4*)&sA[k][ty * 4];
      f32x4 b4 = *(const f32x4*)&sB[k][tx * 4];
#pragma unroll
      for (int i = 0; i < 4; ++i)
#pragma unroll
        for (int jj = 0; jj < 4; ++jj) acc[i][jj] += a4[i] * b4[jj];
    }
  }
#pragma unroll
  for (int i = 0; i < 4; ++i) {
    int m = m0 + ty * 4 + i;
    int b = m >> 6, t = m & 63;
#pragma unroll
    for (int jj = 0; jj < 4; ++jj) {
      int n = n0 + tx * 4 + jj;
      if (n < 2000)
        xz[((size_t)t * B_ + b) * 2000 + n] = acc[i][jj] + bl[n];
    }
  }
}

// ---------------- U prep: uprep[wg][c][k] = bf16(U[k][q*500 + wg*16 + dl]) -------
__global__ __launch_bounds__(256) void k_uprep(const float* __restrict__ U,
                                               short* __restrict__ up) {
  int idx = blockIdx.x * 256 + threadIdx.x;   // 32*64*512 = 1048576 exact
  int k = idx & 511;
  int c = (idx >> 9) & 63;
  int wg = idx >> 15;
  int q = c >> 4, dl = c & 15, dg = wg * 16 + dl;
  float v = 0.f;
  if (dg < H_ && k < H_) v = U[(size_t)k * 2000 + q * H_ + dg];
  up[idx] = bf16rn(v);
}

// ---------------- W_out transpose to bf16: wt[n][k], K-padded -------------------
// grid 8000 = 500 n-tiles(64) x 16 k-tiles(32)
__global__ __launch_bounds__(256) void k_wt(const float* __restrict__ Wo,
                                            short* __restrict__ Wt) {
  __shared__ float s[32][65];
  int nt = blockIdx.x % 500, kt = blockIdx.x / 500;
  int n0 = nt * 64, k0 = kt * 32;
  int tid = threadIdx.x;
  for (int u = tid; u < 2048; u += 256) {
    int kl = u >> 6, nl = u & 63;
    int k = k0 + kl;
    s[kl][nl] = (k < H_) ? Wo[(size_t)k * V_ + n0 + nl] : 0.f;
  }
  __syncthreads();
  for (int u = tid; u < 2048; u += 256) {
    int nl = u >> 5, kl = u & 31;
    Wt[(size_t)(n0 + nl) * KP_ + k0 + kl] = bf16rn(s[kl][nl]);
  }
}

// ---------------- LSTM scan: cooperative, 32 WGs x 128 thr ----------------------
// WG wg owns h-dims [16wg,16wg+16); U slice (64 cols = 4 gates x 16 dims) in LDS.
// Per step: h@U via MFMA 16x16x32 bf16; gates are thread-local (C-frag layout),
// c-state lives in registers. One grid.sync per step.
__global__ __launch_bounds__(128) void k_scan(const short* __restrict__ up,
                                              const float* __restrict__ xz,
                                              short* hpad,
                                              short* __restrict__ hs) {
  __shared__ short Ul[64 * 512];  // XOR-swizzled [c][k] bf16
  int wg = blockIdx.x;
  int tid = threadIdx.x;
  int lane = tid & 63, mtile = tid >> 6;
  int dl = lane & 15, g16 = lane >> 4;

  // stage U slice (swizzled to kill the 16-way ds_read_b128 bank conflict)
  const short* usrc = up + (size_t)wg * 64 * 512;
  for (int u = tid; u < 4096; u += 128) {
    int c = u >> 6, kq = (u & 63) * 8;
    u32 off = ((u32)(c * 512 + kq) * 2) ^ ((u32)(c & 7) << 4);
    *(s16x8*)((char*)Ul + off) = *(const s16x8*)(usrc + c * 512 + kq);
  }
  __syncthreads();

  cg::grid_group gg = cg::this_grid();
  int dg = wg * 16 + dl;
  bool dvalid = dg < H_;
  float cst[4] = {0.f, 0.f, 0.f, 0.f};
  int brow = mtile * 16 + dl;  // A-frag row (= batch index on input side)

  for (int t = 0; t < 64; ++t) {
    const short* hsrc = hpad + (size_t)(t & 1) * (B_ * KP_);
    f32x4 acc[4];
#pragma unroll
    for (int q = 0; q < 4; ++q) acc[q] = (f32x4){0.f, 0.f, 0.f, 0.f};
#pragma unroll
    for (int kk = 0; kk < 16; ++kk) {
      s16x8 a = *(const s16x8*)(hsrc + brow * KP_ + kk * 32 + g16 * 8);
#pragma unroll
      for (int q = 0; q < 4; ++q) {
        int c = q * 16 + dl;
        u32 off = ((u32)(c * 512 + kk * 32 + g16 * 8) * 2) ^ ((u32)(c & 7) << 4);
        s16x8 bfr = *(const s16x8*)((const char*)Ul + off);
        acc[q] = __builtin_amdgcn_mfma_f32_16x16x32_bf16(a, bfr, acc[q], 0, 0, 0);
      }
    }
#pragma unroll
    for (int reg = 0; reg < 4; ++reg) {
      int b = mtile * 16 + g16 * 4 + reg;  // C-frag row
      size_t xb = ((size_t)t * B_ + b) * 2000 + dg;
      float zi = acc[0][reg] + (dvalid ? xz[xb]          : 0.f);
      float zf = acc[1][reg] + (dvalid ? xz[xb + 500]    : 0.f);
      float zc = acc[2][reg] + (dvalid ? xz[xb + 1000]   : 0.f);
      float zo = acc[3][reg] + (dvalid ? xz[xb + 1500]   : 0.f);
      float ig = sigf(zi), fg = sigf(zf), gt = tanhf(zc), og = sigf(zo);
      float cn = fg * cst[reg] + ig * gt;
      cst[reg] = cn;
      float h = og * tanhf(cn);
      if (!dvalid) h = 0.f;
      short hb = bf16rn(h);
      hpad[(size_t)((t + 1) & 1) * (B_ * KP_) + b * KP_ + dg] = hb;
      hs[((size_t)b * T_ + t) * KP_ + dg] = hb;
    }
    gg.sync();
  }
}

// ---------------- logits GEMM (bf16 MFMA 128x128 tile) + exp + row sums ---------
// grid 4000 = 16 m-tiles x 250 n-tiles, 256 thr (4 waves, 64x64 quadrants)
__global__ __launch_bounds__(256) void k_gemm(const short* __restrict__ A,
                                              const short* __restrict__ Bt,
                                              const float* __restrict__ bout,
                                              float* __restrict__ out,
                                              float* __restrict__ rowsum) {
  __shared__ short sA[2][128 * 64];
  __shared__ short sB[2][128 * 64];
  int bid = blockIdx.x;
  int mt = bid & 15, nt = bid >> 4;
  int m0 = mt * 128, n0 = nt * 128;
  int tid = threadIdx.x;
  int lane = tid & 63, w = tid >> 6;
  int wr = w >> 1, wc = w & 1;
  int l15 = lane & 15, l4 = lane >> 4;

  f32x4 acc[4][4];
#pragma unroll
  for (int i = 0; i < 4; ++i)
#pragma unroll
    for (int j = 0; j < 4; ++j) acc[i][j] = (f32x4){0.f, 0.f, 0.f, 0.f};

  auto stage = [&](int kc, int buf) {
    const short* ga = A + (size_t)m0 * KP_ + kc * 64;
    const short* gb = Bt + (size_t)n0 * KP_ + kc * 64;
#pragma unroll
    for (int i = 0; i < 4; ++i) {
      int ch = tid + i * 256;
      int rr = ch >> 3, kq = (ch & 7) * 8;
      gload_lds16(ga + (size_t)rr * KP_ + kq, &sA[buf][rr * 64 + kq]);
      gload_lds16(gb + (size_t)rr * KP_ + kq, &sB[buf][rr * 64 + kq]);
    }
  };

  stage(0, 0);
  __syncthreads();
  int buf = 0;
  for (int kc = 0; kc < 8; ++kc) {
    if (kc < 7) stage(kc + 1, buf ^ 1);
#pragma unroll
    for (int k2 = 0; k2 < 2; ++k2) {
      int kloc = k2 * 32 + l4 * 8;
      s16x8 af[4], bfr[4];
#pragma unroll
      for (int fm = 0; fm < 4; ++fm)
        af[fm] = *(const s16x8*)&sA[buf][(wr * 64 + fm * 16 + l15) * 64 + kloc];
#pragma unroll
      for (int fn = 0; fn < 4; ++fn)
        bfr[fn] = *(const s16x8*)&sB[buf][(wc * 64 + fn * 16 + l15) * 64 + kloc];
#pragma unroll
      for (int fm = 0; fm < 4; ++fm)
#pragma unroll
        for (int fn = 0; fn < 4; ++fn)
          acc[fm][fn] = __builtin_amdgcn_mfma_f32_16x16x32_bf16(af[fm], bfr[fn], acc[fm][fn], 0, 0, 0);
    }
    __syncthreads();
    buf ^= 1;
  }

  float bo4[4];
#pragma unroll
  for (int fn = 0; fn < 4; ++fn) bo4[fn] = bout[n0 + wc * 64 + fn * 16 + l15];

#pragma unroll
  for (int fm = 0; fm < 4; ++fm) {
#pragma unroll
    for (int reg = 0; reg < 4; ++reg) {
      int m = m0 + wr * 64 + fm * 16 + l4 * 4 + reg;
      float s = 0.f;
#pragma unroll
      for (int fn = 0; fn < 4; ++fn) {
        int n = n0 + wc * 64 + fn * 16 + l15;
        float e = __expf(acc[fm][fn][reg] + bo4[fn]);
        out[(size_t)m * V_ + n] = e;
        s += e;
      }
      s += __shfl_xor(s, 1);
      s += __shfl_xor(s, 2);
      s += __shfl_xor(s, 4);
      s += __shfl_xor(s, 8);
      if (l15 == 0) atomicAdd(&rowsum[m], s);
    }
  }
}

// ---------------- normalize: p = e / rowsum ----------------
__global__ __launch_bounds__(256) void k_norm(float* __restrict__ out,
                                              const float* __restrict__ rowsum) {
  size_t i = (size_t)blockIdx.x * 256 + threadIdx.x;  // f4 index; 16,384,000 total
  if (i >= 16384000ul) return;
  int row = (int)(i / 8000);
  float inv = 1.0f / rowsum[row];
  f32x4 v = *(f32x4*)(out + i * 4);
  v.x *= inv; v.y *= inv; v.z *= inv; v.w *= inv;
  *(f32x4*)(out + i * 4) = v;
}

extern "C" void kernel_launch(void* const* d_in, const int* in_sizes, int n_in,
                              void* d_out, int out_size, void* d_ws, size_t ws_size,
                              hipStream_t stream) {
  const float* img  = (const float*)d_in[0];
  const int*   cap  = (const int*)  d_in[1];
  const float* Wimg = (const float*)d_in[2];
  const float* bimg = (const float*)d_in[3];
  const float* emb  = (const float*)d_in[4];
  const float* Wl   = (const float*)d_in[5];
  const float* Ulm  = (const float*)d_in[6];
  const float* bl   = (const float*)d_in[7];
  const float* Wo   = (const float*)d_in[8];
  const float* bo   = (const float*)d_in[9];
  float* out = (float*)d_out;
  char* ws = (char*)d_ws;

  float* x      = (float*)(ws + OFF_X);
  float* xz     = (float*)(ws + OFF_XZ);
  short* hpad   = (short*)(ws + OFF_HPAD);
  short* hs     = (short*)(ws + OFF_HS);
  short* uprep  = (short*)(ws + OFF_UPREP);
  short* wt     = (short*)(ws + OFF_WT);
  float* rowsum = (float*)(ws + OFF_RS);

  k_init<<<1090, 256, 0, stream>>>(bimg, emb, cap, x, (u32*)hpad, rowsum);
  k_uprep<<<4096, 256, 0, stream>>>(Ulm, uprep);
  k_wt<<<8000, 256, 0, stream>>>(Wo, wt);
  k_img<<<128, 256, 0, stream>>>(img, Wimg, x);
  k_xz<<<1024, 256, 0, stream>>>(x, Wl, bl, xz);

  {
    const short* up_p = uprep;
    const float* xz_p = xz;
    short* hpad_p = hpad;
    short* hs_p = hs;
    void* args[] = {&up_p, &xz_p, &hpad_p, &hs_p};
    hipLaunchCooperativeKernel((void*)k_scan, dim3(32), dim3(128), args, 0, stream);
  }

  k_gemm<<<4000, 256, 0, stream>>>(hs, wt, bo, out, rowsum);
  k_norm<<<64000, 256, 0, stream>>>(out, rowsum);
}

// Round 2
// 1007.893 us; speedup vs baseline: 1.2120x; 1.2120x over previous
//
#include <hip/hip_runtime.h>

typedef float f32x4 __attribute__((ext_vector_type(4)));
typedef short s16x8 __attribute__((ext_vector_type(8)));
typedef unsigned int u32;

// ---------------- problem constants ----------------
#define B_    32
#define T_    64
#define TCAP_ 63
#define V_    32000
#define IMGD_ 20480
#define E_    512
#define H_    500
#define KP_   512      // padded K (hidden) for MFMA

// ---------------- ws layout (bytes) ----------------
#define OFF_X      0ul          // x [2048][512] f32
#define OFF_XZ     4194304ul    // xz [64][32][2000] f32 (t-major)
#define OFF_HPAD   20578304ul   // hpad [2][32][512] bf16 (double-buffered h state)
#define OFF_HS     20643840ul   // hs [2048][512] bf16 (all h outputs, K-padded)
#define OFF_UPREP  22740992ul   // uprep [32 wg][64 c][512 k] bf16 (U slices, n-major)
#define OFF_WT     24838144ul   // wt [32000][512] bf16 (W_out^T, K-padded)
#define OFF_RS     57606144ul   // rowsum [2048] f32

__device__ __forceinline__ short bf16rn(float f) {
  u32 u = __float_as_uint(f);
  u += 0x7fff + ((u >> 16) & 1);
  return (short)(u >> 16);
}
__device__ __forceinline__ float sigf(float x) {
  return 1.0f / (1.0f + __expf(-x));
}
__device__ __forceinline__ void gload_lds16(const void* g, void* l) {
  __builtin_amdgcn_global_load_lds((const __attribute__((address_space(1))) void*)g,
                                   (__attribute__((address_space(3))) void*)l, 16, 0, 0);
}

// ---------------- init: x rows (bias / gather), hpad=0, rowsum=0, flags=0 -------
__global__ __launch_bounds__(256) void k_init(const float* __restrict__ bimg,
                                              const float* __restrict__ emb,
                                              const int* __restrict__ cap,
                                              float* __restrict__ x,
                                              u32* __restrict__ hpad_u32,
                                              float* __restrict__ rowsum,
                                              u32* __restrict__ flags) {
  int i = blockIdx.x * 256 + threadIdx.x;
  if (i < 262144) {                 // x: 2048 rows * 128 f4
    int m = i >> 7, j4 = i & 127;
    int b = m >> 6, t = m & 63;
    f32x4 v;
    if (t == 0) v = *(const f32x4*)(bimg + j4 * 4);
    else {
      int r = cap[b * TCAP_ + (t - 1)];
      v = *(const f32x4*)(emb + (size_t)r * E_ + j4 * 4);
    }
    *(f32x4*)(x + (size_t)m * E_ + j4 * 4) = v;
  } else if (i < 262144 + 16384) {  // hpad (both buffers): 65536 B = 16384 u32
    hpad_u32[i - 262144] = 0u;
  } else if (i < 262144 + 16384 + 512) {
    int k = i - 262144 - 16384;
    *(f32x4*)(rowsum + k * 4) = (f32x4){0.f, 0.f, 0.f, 0.f};
  } else if (i < 262144 + 16384 + 512 + 32) {
    flags[i - (262144 + 16384 + 512)] = 0u;   // barrier flags (live in d_out[0..31])
  }
}

// ---------------- image-embed GEMM: atomicAdd into x rows t=0 ----------------
// grid 128 = 8 col-tiles(64) x 16 k-splits(1280), 256 thr
__global__ __launch_bounds__(256) void k_img(const float* __restrict__ img,
                                             const float* __restrict__ W,
                                             float* __restrict__ x) {
  __shared__ float simg[32][128];
  int ct = blockIdx.x & 7;
  int ks = blockIdx.x >> 3;
  int tid = threadIdx.x;
  int j = tid & 63, bq = tid >> 6;
  int col = ct * 64 + j;
  float acc[8] = {0.f, 0.f, 0.f, 0.f, 0.f, 0.f, 0.f, 0.f};
  int kbeg = ks * 1280;
  for (int k0 = kbeg; k0 < kbeg + 1280; k0 += 128) {
    __syncthreads();
    for (int u = tid; u < 32 * 32; u += 256) {
      int b = u >> 5, kq = (u & 31) * 4;
      *(f32x4*)&simg[b][kq] = *(const f32x4*)(img + (size_t)b * IMGD_ + k0 + kq);
    }
    __syncthreads();
    for (int k = 0; k < 128; ++k) {
      float w = W[(size_t)(k0 + k) * E_ + col];
#pragma unroll
      for (int r = 0; r < 8; ++r) acc[r] += simg[bq * 8 + r][k] * w;
    }
  }
#pragma unroll
  for (int r = 0; r < 8; ++r) {
    int b = bq * 8 + r;
    atomicAdd(x + (size_t)b * T_ * E_ + col, acc[r]);
  }
}

// ---------------- xz = x @ W_lstm + b_lstm (f32 tiled), store [t][b][2000] -------
// grid 1024 = 32 m-tiles x 32 n-tiles, 256 thr, thread tile 4x4, BK=32
__global__ __launch_bounds__(256) void k_xz(const float* __restrict__ A,
                                            const float* __restrict__ Wl,
                                            const float* __restrict__ bl,
                                            float* __restrict__ xz) {
  __shared__ float sA[32][68];  // [k][m]
  __shared__ float sB[32][68];  // [k][n]
  int mt = blockIdx.x & 31, nt = blockIdx.x >> 5;
  int m0 = mt * 64, n0 = nt * 64;
  int tid = threadIdx.x;
  int tx = tid & 15, ty = tid >> 4;
  float acc[4][4] = {};
  for (int kb = 0; kb < 512; kb += 32) {
    __syncthreads();
    for (int u = tid; u < 512; u += 256) {           // A: 64 rows x 8 f4
      int r = u >> 3, kq = (u & 7) * 4;
      f32x4 v = *(const f32x4*)(A + (size_t)(m0 + r) * E_ + kb + kq);
      sA[kq + 0][r] = v.x; sA[kq + 1][r] = v.y; sA[kq + 2][r] = v.z; sA[kq + 3][r] = v.w;
    }
    for (int u = tid; u < 512; u += 256) {           // B: 32 k x 16 f4
      int kk = u >> 4, nj = (u & 15) * 4;
      int n = n0 + nj;
      f32x4 v = (f32x4){0.f, 0.f, 0.f, 0.f};
      if (n < 2000) v = *(const f32x4*)(Wl + (size_t)(kb + kk) * 2000 + n);
      *(f32x4*)&sB[kk][nj] = v;
    }
    __syncthreads();
    for (int k = 0; k < 32; ++k) {
      f32x4 a4 = *(const f32x4*)&sA[k][ty * 4];
      f32x4 b4 = *(const f32x4*)&sB[k][tx * 4];
#pragma unroll
      for (int i = 0; i < 4; ++i)
#pragma unroll
        for (int jj = 0; jj < 4; ++jj) acc[i][jj] += a4[i] * b4[jj];
    }
  }
#pragma unroll
  for (int i = 0; i < 4; ++i) {
    int m = m0 + ty * 4 + i;
    int b = m >> 6, t = m & 63;
#pragma unroll
    for (int jj = 0; jj < 4; ++jj) {
      int n = n0 + tx * 4 + jj;
      if (n < 2000)
        xz[((size_t)t * B_ + b) * 2000 + n] = acc[i][jj] + bl[n];
    }
  }
}

// ---------------- U prep: uprep[wg][c][k] = bf16(U[k][q*500 + wg*16 + dl]) -------
__global__ __launch_bounds__(256) void k_uprep(const float* __restrict__ U,
                                               short* __restrict__ up) {
  int idx = blockIdx.x * 256 + threadIdx.x;   // 32*64*512 = 1048576 exact
  int k = idx & 511;
  int c = (idx >> 9) & 63;
  int wg = idx >> 15;
  int q = c >> 4, dl = c & 15, dg = wg * 16 + dl;
  float v = 0.f;
  if (dg < H_ && k < H_) v = U[(size_t)k * 2000 + q * H_ + dg];
  up[idx] = bf16rn(v);
}

// ---------------- W_out transpose to bf16: wt[n][k], K-padded -------------------
// grid 8000 = 500 n-tiles(64) x 16 k-tiles(32)
__global__ __launch_bounds__(256) void k_wt(const float* __restrict__ Wo,
                                            short* __restrict__ Wt) {
  __shared__ float s[32][65];
  int nt = blockIdx.x % 500, kt = blockIdx.x / 500;
  int n0 = nt * 64, k0 = kt * 32;
  int tid = threadIdx.x;
  for (int u = tid; u < 2048; u += 256) {
    int kl = u >> 6, nl = u & 63;
    int k = k0 + kl;
    s[kl][nl] = (k < H_) ? Wo[(size_t)k * V_ + n0 + nl] : 0.f;
  }
  __syncthreads();
  for (int u = tid; u < 2048; u += 256) {
    int nl = u >> 5, kl = u & 31;
    Wt[(size_t)(n0 + nl) * KP_ + k0 + kl] = bf16rn(s[kl][nl]);
  }
}

// ---------------- LSTM scan: cooperative, 32 WGs x 128 thr ----------------------
// WG wg owns h-dims [16wg,16wg+16); U slice (64 cols = 4 gates x 16 dims) in LDS.
// Hand-rolled flag barrier (agent-scope) instead of cg::grid_sync; xz for step
// t+1 prefetched into regs before the barrier so its latency hides in the wait.
__global__ __launch_bounds__(128) void k_scan(const short* __restrict__ up,
                                              const float* __restrict__ xz,
                                              short* hpad,
                                              short* __restrict__ hs,
                                              u32* flags) {
  __shared__ short Ul[64 * 512];  // XOR-swizzled [c][k] bf16
  int wg = blockIdx.x;
  int tid = threadIdx.x;
  int lane = tid & 63, mtile = tid >> 6;
  int dl = lane & 15, g16 = lane >> 4;

  // stage U slice (swizzled to kill the 16-way ds_read_b128 bank conflict)
  const short* usrc = up + (size_t)wg * 64 * 512;
  for (int u = tid; u < 4096; u += 128) {
    int c = u >> 6, kq = (u & 63) * 8;
    u32 off = ((u32)(c * 512 + kq) * 2) ^ ((u32)(c & 7) << 4);
    *(s16x8*)((char*)Ul + off) = *(const s16x8*)(usrc + c * 512 + kq);
  }
  __syncthreads();

  int dg = wg * 16 + dl;
  bool dvalid = dg < H_;
  float cst[4] = {0.f, 0.f, 0.f, 0.f};
  int brow = mtile * 16 + dl;  // A-frag row (= batch index on input side)

  float xzr[4][4];
  auto pf = [&](int t) {
#pragma unroll
    for (int q = 0; q < 4; ++q)
#pragma unroll
      for (int reg = 0; reg < 4; ++reg) {
        int b = mtile * 16 + g16 * 4 + reg;
        xzr[q][reg] = dvalid ? xz[((size_t)t * B_ + b) * 2000 + q * 500 + dg] : 0.f;
      }
  };
  pf(0);

  for (int t = 0; t < 64; ++t) {
    const short* hsrc = hpad + (size_t)(t & 1) * (B_ * KP_);
    f32x4 acc[4];
#pragma unroll
    for (int q = 0; q < 4; ++q) acc[q] = (f32x4){0.f, 0.f, 0.f, 0.f};
#pragma unroll
    for (int kk = 0; kk < 16; ++kk) {
      s16x8 a = *(const s16x8*)(hsrc + brow * KP_ + kk * 32 + g16 * 8);
#pragma unroll
      for (int q = 0; q < 4; ++q) {
        int c = q * 16 + dl;
        u32 off = ((u32)(c * 512 + kk * 32 + g16 * 8) * 2) ^ ((u32)(c & 7) << 4);
        s16x8 bfr = *(const s16x8*)((const char*)Ul + off);
        acc[q] = __builtin_amdgcn_mfma_f32_16x16x32_bf16(a, bfr, acc[q], 0, 0, 0);
      }
    }
#pragma unroll
    for (int reg = 0; reg < 4; ++reg) {
      int b = mtile * 16 + g16 * 4 + reg;  // C-frag row
      float zi = acc[0][reg] + xzr[0][reg];
      float zf = acc[1][reg] + xzr[1][reg];
      float zc = acc[2][reg] + xzr[2][reg];
      float zo = acc[3][reg] + xzr[3][reg];
      float ig = sigf(zi), fg = sigf(zf), gt = tanhf(zc), og = sigf(zo);
      float cn = fg * cst[reg] + ig * gt;
      cst[reg] = cn;
      float h = og * tanhf(cn);
      if (!dvalid) h = 0.f;
      short hb = bf16rn(h);
      hpad[(size_t)((t + 1) & 1) * (B_ * KP_) + b * KP_ + dg] = hb;
      hs[((size_t)b * T_ + t) * KP_ + dg] = hb;
    }

    if (t < 63) {
      pf(t + 1);  // prefetch next xz before the barrier (hides L2/MALL latency)
      u32 target = (u32)(t + 1);
      __builtin_amdgcn_fence(__ATOMIC_RELEASE, "agent");
      __syncthreads();
      if (tid == 0)
        __hip_atomic_store(&flags[wg], target, __ATOMIC_RELAXED, __HIP_MEMORY_SCOPE_AGENT);
      if (tid < 64) {
        u32 v;
        int slot = tid & 31;
        do {
          v = __hip_atomic_load(&flags[slot], __ATOMIC_RELAXED, __HIP_MEMORY_SCOPE_AGENT);
          if (__all(v >= target)) break;
          __builtin_amdgcn_s_sleep(1);
        } while (true);
      }
      __syncthreads();
      __builtin_amdgcn_fence(__ATOMIC_ACQUIRE, "agent");
    }
  }
}

// ---------------- logits GEMM (bf16 MFMA 128x128 tile) + exp + row sums ---------
// grid 4000 = 16 m-tiles x 250 n-tiles, 256 thr (4 waves, 64x64 quadrants)
__global__ __launch_bounds__(256) void k_gemm(const short* __restrict__ A,
                                              const short* __restrict__ Bt,
                                              const float* __restrict__ bout,
                                              float* __restrict__ out,
                                              float* __restrict__ rowsum) {
  __shared__ short sA[2][128 * 64];
  __shared__ short sB[2][128 * 64];
  int bid = blockIdx.x;
  int mt = bid & 15, nt = bid >> 4;
  int m0 = mt * 128, n0 = nt * 128;
  int tid = threadIdx.x;
  int lane = tid & 63, w = tid >> 6;
  int wr = w >> 1, wc = w & 1;
  int l15 = lane & 15, l4 = lane >> 4;

  f32x4 acc[4][4];
#pragma unroll
  for (int i = 0; i < 4; ++i)
#pragma unroll
    for (int j = 0; j < 4; ++j) acc[i][j] = (f32x4){0.f, 0.f, 0.f, 0.f};

  auto stage = [&](int kc, int buf) {
    const short* ga = A + (size_t)m0 * KP_ + kc * 64;
    const short* gb = Bt + (size_t)n0 * KP_ + kc * 64;
#pragma unroll
    for (int i = 0; i < 4; ++i) {
      int ch = tid + i * 256;
      int rr = ch >> 3, kq = (ch & 7) * 8;
      gload_lds16(ga + (size_t)rr * KP_ + kq, &sA[buf][rr * 64 + kq]);
      gload_lds16(gb + (size_t)rr * KP_ + kq, &sB[buf][rr * 64 + kq]);
    }
  };

  stage(0, 0);
  __syncthreads();
  int buf = 0;
  for (int kc = 0; kc < 8; ++kc) {
    if (kc < 7) stage(kc + 1, buf ^ 1);
#pragma unroll
    for (int k2 = 0; k2 < 2; ++k2) {
      int kloc = k2 * 32 + l4 * 8;
      s16x8 af[4], bfr[4];
#pragma unroll
      for (int fm = 0; fm < 4; ++fm)
        af[fm] = *(const s16x8*)&sA[buf][(wr * 64 + fm * 16 + l15) * 64 + kloc];
#pragma unroll
      for (int fn = 0; fn < 4; ++fn)
        bfr[fn] = *(const s16x8*)&sB[buf][(wc * 64 + fn * 16 + l15) * 64 + kloc];
#pragma unroll
      for (int fm = 0; fm < 4; ++fm)
#pragma unroll
        for (int fn = 0; fn < 4; ++fn)
          acc[fm][fn] = __builtin_amdgcn_mfma_f32_16x16x32_bf16(af[fm], bfr[fn], acc[fm][fn], 0, 0, 0);
    }
    __syncthreads();
    buf ^= 1;
  }

  float bo4[4];
#pragma unroll
  for (int fn = 0; fn < 4; ++fn) bo4[fn] = bout[n0 + wc * 64 + fn * 16 + l15];

#pragma unroll
  for (int fm = 0; fm < 4; ++fm) {
#pragma unroll
    for (int reg = 0; reg < 4; ++reg) {
      int m = m0 + wr * 64 + fm * 16 + l4 * 4 + reg;
      float s = 0.f;
#pragma unroll
      for (int fn = 0; fn < 4; ++fn) {
        int n = n0 + wc * 64 + fn * 16 + l15;
        float e = __expf(acc[fm][fn][reg] + bo4[fn]);
        out[(size_t)m * V_ + n] = e;
        s += e;
      }
      s += __shfl_xor(s, 1);
      s += __shfl_xor(s, 2);
      s += __shfl_xor(s, 4);
      s += __shfl_xor(s, 8);
      if (l15 == 0) atomicAdd(&rowsum[m], s);
    }
  }
}

// ---------------- normalize: p = e / rowsum ----------------
__global__ __launch_bounds__(256) void k_norm(float* __restrict__ out,
                                              const float* __restrict__ rowsum) {
  size_t i = (size_t)blockIdx.x * 256 + threadIdx.x;  // f4 index; 16,384,000 total
  if (i >= 16384000ul) return;
  int row = (int)(i / 8000);
  float inv = 1.0f / rowsum[row];
  f32x4 v = *(f32x4*)(out + i * 4);
  v.x *= inv; v.y *= inv; v.z *= inv; v.w *= inv;
  *(f32x4*)(out + i * 4) = v;
}

extern "C" void kernel_launch(void* const* d_in, const int* in_sizes, int n_in,
                              void* d_out, int out_size, void* d_ws, size_t ws_size,
                              hipStream_t stream) {
  const float* img  = (const float*)d_in[0];
  const int*   cap  = (const int*)  d_in[1];
  const float* Wimg = (const float*)d_in[2];
  const float* bimg = (const float*)d_in[3];
  const float* emb  = (const float*)d_in[4];
  const float* Wl   = (const float*)d_in[5];
  const float* Ulm  = (const float*)d_in[6];
  const float* bl   = (const float*)d_in[7];
  const float* Wo   = (const float*)d_in[8];
  const float* bo   = (const float*)d_in[9];
  float* out = (float*)d_out;
  char* ws = (char*)d_ws;

  float* x      = (float*)(ws + OFF_X);
  float* xz     = (float*)(ws + OFF_XZ);
  short* hpad   = (short*)(ws + OFF_HPAD);
  short* hs     = (short*)(ws + OFF_HS);
  short* uprep  = (short*)(ws + OFF_UPREP);
  short* wt     = (short*)(ws + OFF_WT);
  float* rowsum = (float*)(ws + OFF_RS);
  u32*   flags  = (u32*)d_out;   // d_out[0..31]; zeroed by k_init, overwritten by k_gemm

  k_init<<<1090, 256, 0, stream>>>(bimg, emb, cap, x, (u32*)hpad, rowsum, flags);
  k_uprep<<<4096, 256, 0, stream>>>(Ulm, uprep);
  k_wt<<<8000, 256, 0, stream>>>(Wo, wt);
  k_img<<<128, 256, 0, stream>>>(img, Wimg, x);
  k_xz<<<1024, 256, 0, stream>>>(x, Wl, bl, xz);

  {
    const short* up_p = uprep;
    const float* xz_p = xz;
    short* hpad_p = hpad;
    short* hs_p = hs;
    u32* flags_p = flags;
    void* args[] = {&up_p, &xz_p, &hpad_p, &hs_p, &flags_p};
    hipLaunchCooperativeKernel((void*)k_scan, dim3(32), dim3(128), args, 0, stream);
  }

  k_gemm<<<4000, 256, 0, stream>>>(hs, wt, bo, out, rowsum);
  k_norm<<<64000, 256, 0, stream>>>(out, rowsum);
}

// Round 3
// 838.277 us; speedup vs baseline: 1.4573x; 1.2023x over previous
//
#include <hip/hip_runtime.h>

typedef float f32x4 __attribute__((ext_vector_type(4)));
typedef short s16x8 __attribute__((ext_vector_type(8)));
typedef unsigned int u32;
typedef unsigned long long u64;

// ---------------- problem constants ----------------
#define B_    32
#define T_    64
#define TCAP_ 63
#define V_    32000
#define IMGD_ 20480
#define E_    512
#define H_    500
#define KP_   512      // padded K (hidden) for MFMA

// ---------------- ws layout (bytes) ----------------
#define OFF_X      0ul          // x [2048][512] f32
#define OFF_XZ     4194304ul    // xz [64][32][2000] f32 (t-major)
#define OFF_HPAD   20578304ul   // hpad [2][32][512] bf16 (double-buffered h state)
#define OFF_HS     20643840ul   // hs [2048][512] bf16 (all h outputs, K-padded)
#define OFF_UPREP  22740992ul   // uprep [32 wg][64 c][512 k] bf16 (U slices, n-major)
#define OFF_WT     24838144ul   // wt [32000][512] bf16 (W_out^T, K-padded)
#define OFF_RS     57606144ul   // rowsum [2048] f32

__device__ __forceinline__ short bf16rn(float f) {
  u32 u = __float_as_uint(f);
  u += 0x7fff + ((u >> 16) & 1);
  return (short)(u >> 16);
}
__device__ __forceinline__ float sigf(float x) {
  return 1.0f / (1.0f + __expf(-x));
}
__device__ __forceinline__ void gload_lds16(const void* g, void* l) {
  __builtin_amdgcn_global_load_lds((const __attribute__((address_space(1))) void*)g,
                                   (__attribute__((address_space(3))) void*)l, 16, 0, 0);
}

// ---------------- init: x rows (bias / gather), hpad=0, rowsum=0, flags=0 -------
__global__ __launch_bounds__(256) void k_init(const float* __restrict__ bimg,
                                              const float* __restrict__ emb,
                                              const int* __restrict__ cap,
                                              float* __restrict__ x,
                                              u32* __restrict__ hpad_u32,
                                              float* __restrict__ rowsum,
                                              u32* __restrict__ flags) {
  int i = blockIdx.x * 256 + threadIdx.x;
  if (i < 262144) {                 // x: 2048 rows * 128 f4
    int m = i >> 7, j4 = i & 127;
    int b = m >> 6, t = m & 63;
    f32x4 v;
    if (t == 0) v = *(const f32x4*)(bimg + j4 * 4);
    else {
      int r = cap[b * TCAP_ + (t - 1)];
      v = *(const f32x4*)(emb + (size_t)r * E_ + j4 * 4);
    }
    *(f32x4*)(x + (size_t)m * E_ + j4 * 4) = v;
  } else if (i < 262144 + 16384) {  // hpad (both buffers): 65536 B = 16384 u32
    hpad_u32[i - 262144] = 0u;
  } else if (i < 262144 + 16384 + 512) {
    int k = i - 262144 - 16384;
    *(f32x4*)(rowsum + k * 4) = (f32x4){0.f, 0.f, 0.f, 0.f};
  } else if (i < 262144 + 16384 + 512 + 32) {
    flags[i - (262144 + 16384 + 512)] = 0u;   // barrier flags (live in d_out[0..31])
  }
}

// ---------------- image-embed GEMM: atomicAdd into x rows t=0 ----------------
// grid 128 = 8 col-tiles(64) x 16 k-splits(1280), 256 thr
__global__ __launch_bounds__(256) void k_img(const float* __restrict__ img,
                                             const float* __restrict__ W,
                                             float* __restrict__ x) {
  __shared__ float simg[32][128];
  int ct = blockIdx.x & 7;
  int ks = blockIdx.x >> 3;
  int tid = threadIdx.x;
  int j = tid & 63, bq = tid >> 6;
  int col = ct * 64 + j;
  float acc[8] = {0.f, 0.f, 0.f, 0.f, 0.f, 0.f, 0.f, 0.f};
  int kbeg = ks * 1280;
  for (int k0 = kbeg; k0 < kbeg + 1280; k0 += 128) {
    __syncthreads();
    for (int u = tid; u < 32 * 32; u += 256) {
      int b = u >> 5, kq = (u & 31) * 4;
      *(f32x4*)&simg[b][kq] = *(const f32x4*)(img + (size_t)b * IMGD_ + k0 + kq);
    }
    __syncthreads();
    for (int k = 0; k < 128; ++k) {
      float w = W[(size_t)(k0 + k) * E_ + col];
#pragma unroll
      for (int r = 0; r < 8; ++r) acc[r] += simg[bq * 8 + r][k] * w;
    }
  }
#pragma unroll
  for (int r = 0; r < 8; ++r) {
    int b = bq * 8 + r;
    atomicAdd(x + (size_t)b * T_ * E_ + col, acc[r]);
  }
}

// ---------------- xz = x @ W_lstm + b_lstm (f32 tiled), store [t][b][2000] -------
// grid 1024 = 32 m-tiles x 32 n-tiles, 256 thr, thread tile 4x4, BK=32
__global__ __launch_bounds__(256) void k_xz(const float* __restrict__ A,
                                            const float* __restrict__ Wl,
                                            const float* __restrict__ bl,
                                            float* __restrict__ xz) {
  __shared__ float sA[32][68];  // [k][m]
  __shared__ float sB[32][68];  // [k][n]
  int mt = blockIdx.x & 31, nt = blockIdx.x >> 5;
  int m0 = mt * 64, n0 = nt * 64;
  int tid = threadIdx.x;
  int tx = tid & 15, ty = tid >> 4;
  float acc[4][4] = {};
  for (int kb = 0; kb < 512; kb += 32) {
    __syncthreads();
    for (int u = tid; u < 512; u += 256) {           // A: 64 rows x 8 f4
      int r = u >> 3, kq = (u & 7) * 4;
      f32x4 v = *(const f32x4*)(A + (size_t)(m0 + r) * E_ + kb + kq);
      sA[kq + 0][r] = v.x; sA[kq + 1][r] = v.y; sA[kq + 2][r] = v.z; sA[kq + 3][r] = v.w;
    }
    for (int u = tid; u < 512; u += 256) {           // B: 32 k x 16 f4
      int kk = u >> 4, nj = (u & 15) * 4;
      int n = n0 + nj;
      f32x4 v = (f32x4){0.f, 0.f, 0.f, 0.f};
      if (n < 2000) v = *(const f32x4*)(Wl + (size_t)(kb + kk) * 2000 + n);
      *(f32x4*)&sB[kk][nj] = v;
    }
    __syncthreads();
    for (int k = 0; k < 32; ++k) {
      f32x4 a4 = *(const f32x4*)&sA[k][ty * 4];
      f32x4 b4 = *(const f32x4*)&sB[k][tx * 4];
#pragma unroll
      for (int i = 0; i < 4; ++i)
#pragma unroll
        for (int jj = 0; jj < 4; ++jj) acc[i][jj] += a4[i] * b4[jj];
    }
  }
#pragma unroll
  for (int i = 0; i < 4; ++i) {
    int m = m0 + ty * 4 + i;
    int b = m >> 6, t = m & 63;
#pragma unroll
    for (int jj = 0; jj < 4; ++jj) {
      int n = n0 + tx * 4 + jj;
      if (n < 2000)
        xz[((size_t)t * B_ + b) * 2000 + n] = acc[i][jj] + bl[n];
    }
  }
}

// ---------------- U prep: uprep[wg][c][k] = bf16(U[k][q*500 + wg*16 + dl]) -------
__global__ __launch_bounds__(256) void k_uprep(const float* __restrict__ U,
                                               short* __restrict__ up) {
  int idx = blockIdx.x * 256 + threadIdx.x;   // 32*64*512 = 1048576 exact
  int k = idx & 511;
  int c = (idx >> 9) & 63;
  int wg = idx >> 15;
  int q = c >> 4, dl = c & 15, dg = wg * 16 + dl;
  float v = 0.f;
  if (dg < H_ && k < H_) v = U[(size_t)k * 2000 + q * H_ + dg];
  up[idx] = bf16rn(v);
}

// ---------------- W_out transpose to bf16: wt[n][k], K-padded -------------------
// grid 8000 = 500 n-tiles(64) x 16 k-tiles(32)
__global__ __launch_bounds__(256) void k_wt(const float* __restrict__ Wo,
                                            short* __restrict__ Wt) {
  __shared__ float s[32][65];
  int nt = blockIdx.x % 500, kt = blockIdx.x / 500;
  int n0 = nt * 64, k0 = kt * 32;
  int tid = threadIdx.x;
  for (int u = tid; u < 2048; u += 256) {
    int kl = u >> 6, nl = u & 63;
    int k = k0 + kl;
    s[kl][nl] = (k < H_) ? Wo[(size_t)k * V_ + n0 + nl] : 0.f;
  }
  __syncthreads();
  for (int u = tid; u < 2048; u += 256) {
    int nl = u >> 5, kl = u & 31;
    Wt[(size_t)(n0 + nl) * KP_ + k0 + kl] = bf16rn(s[kl][nl]);
  }
}

// ---------------- LSTM scan: cooperative, 32 WGs x 128 thr ----------------------
// Fence-free device coherence: h exchanged via relaxed AGENT-scope atomics
// (sc1 write-through stores to MALL, sc1 bypass loads from MALL). No
// buffer_wbl2 / buffer_inv per step. __syncthreads() drains vmcnt so the
// flag store is ordered after the h stores. t=0 skips the h@U MFMA (h==0).
__global__ __launch_bounds__(128) void k_scan(const short* __restrict__ up,
                                              const float* __restrict__ xz,
                                              short* hpad,
                                              short* __restrict__ hs,
                                              u32* flags) {
  __shared__ short Ul[64 * 512];  // XOR-swizzled [c][k] bf16
  int wg = blockIdx.x;
  int tid = threadIdx.x;
  int lane = tid & 63, mtile = tid >> 6;
  int dl = lane & 15, g16 = lane >> 4;

  // stage U slice (swizzled to kill the 16-way ds_read_b128 bank conflict)
  const short* usrc = up + (size_t)wg * 64 * 512;
  for (int u = tid; u < 4096; u += 128) {
    int c = u >> 6, kq = (u & 63) * 8;
    u32 off = ((u32)(c * 512 + kq) * 2) ^ ((u32)(c & 7) << 4);
    *(s16x8*)((char*)Ul + off) = *(const s16x8*)(usrc + c * 512 + kq);
  }
  __syncthreads();

  int dg = wg * 16 + dl;
  bool dvalid = dg < H_;
  float cst[4] = {0.f, 0.f, 0.f, 0.f};
  int brow = mtile * 16 + dl;  // A-frag row (= batch index on input side)

  float xzr[4][4];
  auto pf = [&](int t) {
#pragma unroll
    for (int q = 0; q < 4; ++q)
#pragma unroll
      for (int reg = 0; reg < 4; ++reg) {
        int b = mtile * 16 + g16 * 4 + reg;
        xzr[q][reg] = dvalid ? xz[((size_t)t * B_ + b) * 2000 + q * 500 + dg] : 0.f;
      }
  };
  pf(0);

  for (int t = 0; t < 64; ++t) {
    f32x4 acc[4];
#pragma unroll
    for (int q = 0; q < 4; ++q) acc[q] = (f32x4){0.f, 0.f, 0.f, 0.f};

    if (t > 0) {
      const short* hsrc = hpad + (size_t)(t & 1) * (B_ * KP_);
      u64 q0[16], q1[16];
#pragma unroll
      for (int kk = 0; kk < 16; ++kk) {
        const u64* p = (const u64*)(hsrc + brow * KP_ + kk * 32 + g16 * 8);
        q0[kk] = __hip_atomic_load(p,     __ATOMIC_RELAXED, __HIP_MEMORY_SCOPE_AGENT);
        q1[kk] = __hip_atomic_load(p + 1, __ATOMIC_RELAXED, __HIP_MEMORY_SCOPE_AGENT);
      }
#pragma unroll
      for (int kk = 0; kk < 16; ++kk) {
        union { s16x8 v; u64 q[2]; } fr;
        fr.q[0] = q0[kk]; fr.q[1] = q1[kk];
#pragma unroll
        for (int q = 0; q < 4; ++q) {
          int c = q * 16 + dl;
          u32 off = ((u32)(c * 512 + kk * 32 + g16 * 8) * 2) ^ ((u32)(c & 7) << 4);
          s16x8 bfr = *(const s16x8*)((const char*)Ul + off);
          acc[q] = __builtin_amdgcn_mfma_f32_16x16x32_bf16(fr.v, bfr, acc[q], 0, 0, 0);
        }
      }
    }

    short hb4[4];
#pragma unroll
    for (int reg = 0; reg < 4; ++reg) {
      float zi = acc[0][reg] + xzr[0][reg];
      float zf = acc[1][reg] + xzr[1][reg];
      float zc = acc[2][reg] + xzr[2][reg];
      float zo = acc[3][reg] + xzr[3][reg];
      float ig = sigf(zi), fg = sigf(zf), gt = tanhf(zc), og = sigf(zo);
      float cn = fg * cst[reg] + ig * gt;
      cst[reg] = cn;
      float h = og * tanhf(cn);
      if (!dvalid) h = 0.f;
      hb4[reg] = bf16rn(h);
    }

    // pack h pairs (dg, dg^1) via shuffle -> one u32 agent-scope store each
    short* hnext = hpad + (size_t)((t + 1) & 1) * (B_ * KP_);
#pragma unroll
    for (int reg = 0; reg < 4; ++reg) {
      int mine = (int)(u32)(unsigned short)hb4[reg];
      int oth = __shfl_xor(mine, 1);
      if ((dl & 1) == 0) {
        int b = mtile * 16 + g16 * 4 + reg;
        u32 val = ((u32)mine) | ((u32)oth << 16);
        __hip_atomic_store((u32*)hnext + ((b * KP_ + dg) >> 1), val,
                           __ATOMIC_RELAXED, __HIP_MEMORY_SCOPE_AGENT);
      }
    }

    if (t < 63) {
      __syncthreads();   // vmcnt(0) drain: h stores acked at MALL before flag
      if (tid == 0)
        __hip_atomic_store(&flags[wg], (u32)(t + 1),
                           __ATOMIC_RELAXED, __HIP_MEMORY_SCOPE_AGENT);
      asm volatile("" ::: "memory");
      // overlapped with the barrier wait: hs stores + next-step xz prefetch
#pragma unroll
      for (int reg = 0; reg < 4; ++reg) {
        int b = mtile * 16 + g16 * 4 + reg;
        hs[((size_t)b * T_ + t) * KP_ + dg] = hb4[reg];
      }
      pf(t + 1);
      if (tid < 64) {
        u32 target = (u32)(t + 1);
        int slot = tid & 31;
        while (true) {
          u32 v = __hip_atomic_load(&flags[slot], __ATOMIC_RELAXED,
                                    __HIP_MEMORY_SCOPE_AGENT);
          if (__all(v >= target)) break;
          __builtin_amdgcn_s_sleep(1);
        }
      }
      __syncthreads();
    } else {
#pragma unroll
      for (int reg = 0; reg < 4; ++reg) {
        int b = mtile * 16 + g16 * 4 + reg;
        hs[((size_t)b * T_ + t) * KP_ + dg] = hb4[reg];
      }
    }
  }
}

// ---------------- logits GEMM (bf16 MFMA 128x128 tile), two phases --------------
// PHASE 0: exp + per-row atomic sums only (no out write).
// PHASE 1: bit-identical recompute, writes p = e / rowsum. Replaces k_norm.
// grid 4000 = 16 m-tiles x 250 n-tiles, 256 thr (4 waves, 64x64 quadrants)
template <int PHASE>
__global__ __launch_bounds__(256) void k_gemm(const short* __restrict__ A,
                                              const short* __restrict__ Bt,
                                              const float* __restrict__ bout,
                                              float* __restrict__ out,
                                              float* __restrict__ rowsum) {
  __shared__ short sA[2][128 * 64];
  __shared__ short sB[2][128 * 64];
  int bid = blockIdx.x;
  int mt = bid & 15, nt = bid >> 4;
  int m0 = mt * 128, n0 = nt * 128;
  int tid = threadIdx.x;
  int lane = tid & 63, w = tid >> 6;
  int wr = w >> 1, wc = w & 1;
  int l15 = lane & 15, l4 = lane >> 4;

  f32x4 acc[4][4];
#pragma unroll
  for (int i = 0; i < 4; ++i)
#pragma unroll
    for (int j = 0; j < 4; ++j) acc[i][j] = (f32x4){0.f, 0.f, 0.f, 0.f};

  auto stage = [&](int kc, int buf) {
    const short* ga = A + (size_t)m0 * KP_ + kc * 64;
    const short* gb = Bt + (size_t)n0 * KP_ + kc * 64;
#pragma unroll
    for (int i = 0; i < 4; ++i) {
      int ch = tid + i * 256;
      int rr = ch >> 3, kq = (ch & 7) * 8;
      gload_lds16(ga + (size_t)rr * KP_ + kq, &sA[buf][rr * 64 + kq]);
      gload_lds16(gb + (size_t)rr * KP_ + kq, &sB[buf][rr * 64 + kq]);
    }
  };

  stage(0, 0);
  __syncthreads();
  int buf = 0;
  for (int kc = 0; kc < 8; ++kc) {
    if (kc < 7) stage(kc + 1, buf ^ 1);
#pragma unroll
    for (int k2 = 0; k2 < 2; ++k2) {
      int kloc = k2 * 32 + l4 * 8;
      s16x8 af[4], bfr[4];
#pragma unroll
      for (int fm = 0; fm < 4; ++fm)
        af[fm] = *(const s16x8*)&sA[buf][(wr * 64 + fm * 16 + l15) * 64 + kloc];
#pragma unroll
      for (int fn = 0; fn < 4; ++fn)
        bfr[fn] = *(const s16x8*)&sB[buf][(wc * 64 + fn * 16 + l15) * 64 + kloc];
#pragma unroll
      for (int fm = 0; fm < 4; ++fm)
#pragma unroll
        for (int fn = 0; fn < 4; ++fn)
          acc[fm][fn] = __builtin_amdgcn_mfma_f32_16x16x32_bf16(af[fm], bfr[fn], acc[fm][fn], 0, 0, 0);
    }
    __syncthreads();
    buf ^= 1;
  }

  float bo4[4];
#pragma unroll
  for (int fn = 0; fn < 4; ++fn) bo4[fn] = bout[n0 + wc * 64 + fn * 16 + l15];

#pragma unroll
  for (int fm = 0; fm < 4; ++fm) {
#pragma unroll
    for (int reg = 0; reg < 4; ++reg) {
      int m = m0 + wr * 64 + fm * 16 + l4 * 4 + reg;
      if constexpr (PHASE == 0) {
        float s = 0.f;
#pragma unroll
        for (int fn = 0; fn < 4; ++fn) {
          float e = __expf(acc[fm][fn][reg] + bo4[fn]);
          s += e;
        }
        s += __shfl_xor(s, 1);
        s += __shfl_xor(s, 2);
        s += __shfl_xor(s, 4);
        s += __shfl_xor(s, 8);
        if (l15 == 0) atomicAdd(&rowsum[m], s);
      } else {
        float inv = 1.0f / rowsum[m];
#pragma unroll
        for (int fn = 0; fn < 4; ++fn) {
          int n = n0 + wc * 64 + fn * 16 + l15;
          float e = __expf(acc[fm][fn][reg] + bo4[fn]);
          out[(size_t)m * V_ + n] = e * inv;
        }
      }
    }
  }
}

extern "C" void kernel_launch(void* const* d_in, const int* in_sizes, int n_in,
                              void* d_out, int out_size, void* d_ws, size_t ws_size,
                              hipStream_t stream) {
  const float* img  = (const float*)d_in[0];
  const int*   cap  = (const int*)  d_in[1];
  const float* Wimg = (const float*)d_in[2];
  const float* bimg = (const float*)d_in[3];
  const float* emb  = (const float*)d_in[4];
  const float* Wl   = (const float*)d_in[5];
  const float* Ulm  = (const float*)d_in[6];
  const float* bl   = (const float*)d_in[7];
  const float* Wo   = (const float*)d_in[8];
  const float* bo   = (const float*)d_in[9];
  float* out = (float*)d_out;
  char* ws = (char*)d_ws;

  float* x      = (float*)(ws + OFF_X);
  float* xz     = (float*)(ws + OFF_XZ);
  short* hpad   = (short*)(ws + OFF_HPAD);
  short* hs     = (short*)(ws + OFF_HS);
  short* uprep  = (short*)(ws + OFF_UPREP);
  short* wt     = (short*)(ws + OFF_WT);
  float* rowsum = (float*)(ws + OFF_RS);
  u32*   flags  = (u32*)d_out;   // d_out[0..31]; zeroed by k_init, overwritten by k_gemm<1>

  k_init<<<1090, 256, 0, stream>>>(bimg, emb, cap, x, (u32*)hpad, rowsum, flags);
  k_uprep<<<4096, 256, 0, stream>>>(Ulm, uprep);
  k_wt<<<8000, 256, 0, stream>>>(Wo, wt);
  k_img<<<128, 256, 0, stream>>>(img, Wimg, x);
  k_xz<<<1024, 256, 0, stream>>>(x, Wl, bl, xz);

  {
    const short* up_p = uprep;
    const float* xz_p = xz;
    short* hpad_p = hpad;
    short* hs_p = hs;
    u32* flags_p = flags;
    void* args[] = {&up_p, &xz_p, &hpad_p, &hs_p, &flags_p};
    hipLaunchCooperativeKernel((void*)k_scan, dim3(32), dim3(128), args, 0, stream);
  }

  k_gemm<0><<<4000, 256, 0, stream>>>(hs, wt, bo, out, rowsum);
  k_gemm<1><<<4000, 256, 0, stream>>>(hs, wt, bo, out, rowsum);
}